// Round 16
// baseline (170.982 us; speedup 1.0000x reference)
//
#include <hip/hip_runtime.h>
#include <math.h>

#define NE  8
#define HID 256

typedef __attribute__((ext_vector_type(8)))  short short8;
typedef __attribute__((ext_vector_type(16))) float f32x16;

static __device__ __forceinline__ unsigned short f2bf(float f) {
    unsigned int u = __float_as_uint(f);
    return (unsigned short)((u + 0x7FFFu + ((u >> 16) & 1u)) >> 16);
}

static __device__ __forceinline__ short8 pack8(float4 a, float4 b) {
    short8 r;
    r[0] = (short)f2bf(a.x); r[1] = (short)f2bf(a.y);
    r[2] = (short)f2bf(a.z); r[3] = (short)f2bf(a.w);
    r[4] = (short)f2bf(b.x); r[5] = (short)f2bf(b.y);
    r[6] = (short)f2bf(b.z); r[7] = (short)f2bf(b.w);
    return r;
}

// ---------------------------------------------------------------------------
// Kernel 1 (blocks 0..1023): W1 [E][128][256] -> bf16 frag-linear.
//   frag (e, hrt<8, kt<8): [lane][j] = W1[e][kt*16+(lane>>5)*8+j][hrt*32+(lane&31)]
// Block 1024: pk table [e][hrt][q][g][8] f32: j<4 -> b1[h], j>=4 -> W2[h].
// ---------------------------------------------------------------------------
__global__ void prep_w1(const float* __restrict__ W1, const float* __restrict__ b1,
                        const float* __restrict__ W2,
                        unsigned short* __restrict__ wfr, float* __restrict__ pk) {
    if (blockIdx.x < 1024) {
        int f = blockIdx.x * 256 + threadIdx.x;     // 262144 total
        int j   = f & 7;
        int l   = (f >> 3) & 63;
        int kt  = (f >> 9) & 7;
        int hrt = (f >> 12) & 7;
        int e   = f >> 15;
        int k = kt * 16 + ((l >> 5) * 8) + j;
        int h = hrt * 32 + (l & 31);
        wfr[f] = f2bf(W1[((size_t)e * 128 + k) * HID + h]);
    } else {
        for (int i = threadIdx.x; i < 4096; i += 256) {
            int j   = i & 7;
            int g   = (i >> 3) & 1;
            int q   = (i >> 4) & 3;
            int hrt = (i >> 6) & 7;
            int e   = i >> 9;
            int h = hrt * 32 + q * 8 + g * 4 + (j & 3);
            pk[i] = (j < 4) ? b1[e * HID + h] : W2[e * HID + h];
        }
    }
}

// ---------------------------------------------------------------------------
// Kernel 2: gating softmax (exact fp32) + experts_used + per-block partials.
// Also zeroes pred (2-addend atomicAdd determinism on zeroed slots).
// ---------------------------------------------------------------------------
__global__ void gates_kernel(const float* __restrict__ cp,
                             float* __restrict__ gates_out,
                             float* __restrict__ used_out,
                             float* __restrict__ part,
                             float* __restrict__ pred_zero) {
    __shared__ float wp_[4][16];
    int tid = threadIdx.x;
    int b = blockIdx.x * 256 + tid;

    pred_zero[b] = 0.f;

    float g[8];
    {
        const float4* c4 = (const float4*)(cp + (size_t)b * NE);
        float4 a0 = c4[0], a1 = c4[1];
        g[0]=a0.x; g[1]=a0.y; g[2]=a0.z; g[3]=a0.w;
        g[4]=a1.x; g[5]=a1.y; g[6]=a1.z; g[7]=a1.w;
    }
    float m = g[0];
    #pragma unroll
    for (int i = 1; i < 8; ++i) m = fmaxf(m, g[i]);
    float s = 0.f;
    #pragma unroll
    for (int i = 0; i < 8; ++i) { g[i] = __expf(g[i] - m); s += g[i]; }
    float inv = 1.f / s;
    #pragma unroll
    for (int i = 0; i < 8; ++i) g[i] *= inv;

    {
        float4 o0 = make_float4(g[0], g[1], g[2], g[3]);
        float4 o1 = make_float4(g[4], g[5], g[6], g[7]);
        float4* g4 = (float4*)(gates_out + (size_t)b * NE);
        g4[0] = o0; g4[1] = o1;
    }
    float v[16];
    float used = 0.f;
    #pragma unroll
    for (int i = 0; i < 8; ++i) {
        float a = (g[i] > 0.01f) ? 1.f : 0.f;
        used += a;
        v[i] = g[i];
        v[8 + i] = a;
    }
    used_out[b] = used;

    #pragma unroll
    for (int d = 32; d >= 1; d >>= 1)
        #pragma unroll
        for (int i = 0; i < 16; ++i)
            v[i] += __shfl_down(v[i], d, 64);
    int lane = tid & 63, wid = tid >> 6;
    if (lane == 0)
        #pragma unroll
        for (int i = 0; i < 16; ++i) wp_[wid][i] = v[i];
    __syncthreads();
    if (tid < 16)
        part[(size_t)blockIdx.x * 16 + tid] =
            wp_[0][tid] + wp_[1][tid] + wp_[2][tid] + wp_[3][tid];
}

// 512-thread deterministic reduce: 32 partial-threads per output, LDS tree.
__global__ void reduce_kernel(const float* __restrict__ part,
                              float* __restrict__ inf_out,
                              float* __restrict__ cnt_out) {
    __shared__ float red[16][32];
    int t = threadIdx.x;
    int o = t & 15, i = t >> 4;
    float s = 0.f;
    for (int k = i; k < 512; k += 32) s += part[(size_t)k * 16 + o];
    red[o][i] = s;
    __syncthreads();
    if (t < 16) {
        float r = 0.f;
        #pragma unroll
        for (int j = 0; j < 32; ++j) r += red[t][j];
        if (t < 8) inf_out[t] = r;
        else       cnt_out[t - 8] = r;
    }
}

// ---------------------------------------------------------------------------
// Kernel 4: main MoE = r9 loop body in a SINGLE 16-wave block per CU.
// 256 blocks x 1024 thr: tb = blockIdx&127 (1024 tokens), grp = blockIdx>>7
// (4 experts). 16 waves = 4 waves/SIMD (VGPR ~90, 4x92=368 <= 512) -- the
// one config giving >2 waves/SIMD without spill (r8's failure was the
// (1024,4) reg clamp; (1024,1) leaves the allocator free). LDS 144KB:
// 2x64KB W1 dbuf + 16KB f32 pks (r15 lesson: bf16 pkh + rotation cost
// VALU; reverted). ONE barrier per expert; epilogue of hrt-1 interleaved
// into MFMAs of hrt. Pairs (b, b+128) share x, same XCD (128%8==0).
// pred combined via 2-addend atomicAdd on zeroed slots (deterministic).
// ---------------------------------------------------------------------------
#define MFMA_ __builtin_amdgcn_mfma_f32_32x32x16_bf16

#define STEP(HRT, C0, C1, P0, P1, PH) { \
    float4 b1q, w2q; \
    _Pragma("unroll") \
    for (int kt = 0; kt < 8; ++kt) { \
        short8 w = *(const short8*)&W1s[p][(((HRT) * 8 + kt) * 64 + lane) * 8]; \
        C0 = MFMA_(w, xf[0][kt], C0, 0, 0, 0); \
        C1 = MFMA_(w, xf[1][kt], C1, 0, 0, 0); \
        int q = kt >> 1; \
        if ((kt & 1) == 0) { \
            int base = (((e * 8 + (PH)) * 4 + q) * 2 + g) * 8; \
            b1q = *(const float4*)&pks[base]; \
            w2q = *(const float4*)&pks[base + 4]; \
            ye0 = fmaf(fmaxf(P0[q * 4 + 0] + b1q.x, 0.f), w2q.x, ye0); \
            ye1 = fmaf(fmaxf(P1[q * 4 + 0] + b1q.x, 0.f), w2q.x, ye1); \
            ye0 = fmaf(fmaxf(P0[q * 4 + 1] + b1q.y, 0.f), w2q.y, ye0); \
            ye1 = fmaf(fmaxf(P1[q * 4 + 1] + b1q.y, 0.f), w2q.y, ye1); \
        } else { \
            ye0 = fmaf(fmaxf(P0[q * 4 + 2] + b1q.z, 0.f), w2q.z, ye0); \
            ye1 = fmaf(fmaxf(P1[q * 4 + 2] + b1q.z, 0.f), w2q.z, ye1); \
            ye0 = fmaf(fmaxf(P0[q * 4 + 3] + b1q.w, 0.f), w2q.w, ye0); \
            ye1 = fmaf(fmaxf(P1[q * 4 + 3] + b1q.w, 0.f), w2q.w, ye1); \
        } \
    } }

#define STEP_NOEPI(HRT, C0, C1) { \
    _Pragma("unroll") \
    for (int kt = 0; kt < 8; ++kt) { \
        short8 w = *(const short8*)&W1s[p][(((HRT) * 8 + kt) * 64 + lane) * 8]; \
        C0 = MFMA_(w, xf[0][kt], C0, 0, 0, 0); \
        C1 = MFMA_(w, xf[1][kt], C1, 0, 0, 0); \
    } }

#define EPI_TAIL(P0, P1, PH) { \
    _Pragma("unroll") \
    for (int q = 0; q < 4; ++q) { \
        int base = (((e * 8 + (PH)) * 4 + q) * 2 + g) * 8; \
        float4 b1q = *(const float4*)&pks[base]; \
        float4 w2q = *(const float4*)&pks[base + 4]; \
        ye0 = fmaf(fmaxf(P0[q * 4 + 0] + b1q.x, 0.f), w2q.x, ye0); \
        ye1 = fmaf(fmaxf(P1[q * 4 + 0] + b1q.x, 0.f), w2q.x, ye1); \
        ye0 = fmaf(fmaxf(P0[q * 4 + 1] + b1q.y, 0.f), w2q.y, ye0); \
        ye1 = fmaf(fmaxf(P1[q * 4 + 1] + b1q.y, 0.f), w2q.y, ye1); \
        ye0 = fmaf(fmaxf(P0[q * 4 + 2] + b1q.z, 0.f), w2q.z, ye0); \
        ye1 = fmaf(fmaxf(P1[q * 4 + 2] + b1q.z, 0.f), w2q.z, ye1); \
        ye0 = fmaf(fmaxf(P0[q * 4 + 3] + b1q.w, 0.f), w2q.w, ye0); \
        ye1 = fmaf(fmaxf(P1[q * 4 + 3] + b1q.w, 0.f), w2q.w, ye1); \
    } }

__global__ __launch_bounds__(1024, 1)
void moe_main(const float* __restrict__ x,
              const unsigned short* __restrict__ wfr,
              const float* __restrict__ pk,
              const float* __restrict__ b2,
              const float* __restrict__ gates,
              float* __restrict__ pred_out) {
    __shared__ unsigned short W1s[2][8 * 8 * 64 * 8];   // 2 x 64 KB
    __shared__ float pks[4096];                         // 16 KB

    const int tid  = threadIdx.x;
    const int lane = tid & 63;
    const int wid  = tid >> 6;          // 0..15
    const int g    = lane >> 5;
    const int col  = lane & 31;
    const int tb   = blockIdx.x & 127;
    const int grp  = blockIdx.x >> 7;   // expert group: e in [grp*4, grp*4+4)
    const int tw   = tb * 1024 + wid * 64;   // wave token base
    const int e0   = grp * 4;

    // ---- stage expert e0 into buf 0 (64 KB = 1024 thr x 4 x 16B)
    {
        const char* src = (const char*)wfr + (size_t)e0 * 65536 + tid * 16;
        char* dst = (char*)&W1s[0][0] + tid * 16;
        #pragma unroll
        for (int i = 0; i < 4; ++i)
            __builtin_amdgcn_global_load_lds(
                (const __attribute__((address_space(1))) unsigned int*)(src + i * 16384),
                (__attribute__((address_space(3))) unsigned int*)(dst + i * 16384),
                16, 0, 0);
    }
    // ---- pk table -> LDS (1024 float4 over 1024 threads)
    ((float4*)pks)[tid] = ((const float4*)pk)[tid];

    // ---- x fragments -> registers: frag (tt<2, kt<8): token=tw+tt*32+col,
    //      k = kt*16 + g*8 + j
    short8 xf[2][8];
    #pragma unroll
    for (int tt = 0; tt < 2; ++tt) {
        const float* xr = x + ((size_t)(tw + tt * 32 + col)) * 128 + g * 8;
        #pragma unroll
        for (int kt = 0; kt < 8; ++kt) {
            float4 a = *(const float4*)(xr + kt * 16);
            float4 b = *(const float4*)(xr + kt * 16 + 4);
            xf[tt][kt] = pack8(a, b);
        }
    }

    float pred0 = 0.f, pred1 = 0.f;
    int p = 0;
    __syncthreads();   // drains: stage(e0), pks, x loads

    for (int ee = 0; ee < 4; ++ee) {
        const int e = e0 + ee;
        if (ee < 3) {   // stage next expert into other buffer (drained at barrier)
            const char* src = (const char*)wfr + (size_t)(e + 1) * 65536 + tid * 16;
            char* dst = (char*)&W1s[p ^ 1][0] + tid * 16;
            #pragma unroll
            for (int i = 0; i < 4; ++i)
                __builtin_amdgcn_global_load_lds(
                    (const __attribute__((address_space(1))) unsigned int*)(src + i * 16384),
                    (__attribute__((address_space(3))) unsigned int*)(dst + i * 16384),
                    16, 0, 0);
        }

        // hoisted per-expert scalars (latency hides under MFMA stream)
        float gt0 = gates[(size_t)(tw + col) * NE + e];
        float gt1 = gates[(size_t)(tw + 32 + col) * NE + e];
        float bb  = b2[e];

        float ye0 = 0.f, ye1 = 0.f;
        f32x16 a0, a1, c0, c1;

        a0 = (f32x16)0.0f; a1 = (f32x16)0.0f;
        STEP_NOEPI(0, a0, a1)
        c0 = (f32x16)0.0f; c1 = (f32x16)0.0f;
        STEP(1, c0, c1, a0, a1, 0)
        a0 = (f32x16)0.0f; a1 = (f32x16)0.0f;
        STEP(2, a0, a1, c0, c1, 1)
        c0 = (f32x16)0.0f; c1 = (f32x16)0.0f;
        STEP(3, c0, c1, a0, a1, 2)
        a0 = (f32x16)0.0f; a1 = (f32x16)0.0f;
        STEP(4, a0, a1, c0, c1, 3)
        c0 = (f32x16)0.0f; c1 = (f32x16)0.0f;
        STEP(5, c0, c1, a0, a1, 4)
        a0 = (f32x16)0.0f; a1 = (f32x16)0.0f;
        STEP(6, a0, a1, c0, c1, 5)
        c0 = (f32x16)0.0f; c1 = (f32x16)0.0f;
        STEP(7, c0, c1, a0, a1, 6)
        EPI_TAIL(c0, c1, 7)

        // fold halves, sigmoid, gate-weight
        {
            float s0 = ye0 + __shfl_xor(ye0, 32, 64) + bb;
            float s1 = ye1 + __shfl_xor(ye1, 32, 64) + bb;
            float yv0 = 1.f / (1.f + __expf(-s0));
            float yv1 = 1.f / (1.f + __expf(-s1));
            pred0 = fmaf(gt0, yv0, pred0);
            pred1 = fmaf(gt1, yv1, pred1);
        }

        __syncthreads();   // buf[p] reads done; stage(e+1) drained
        p ^= 1;
    }

    // combine the two expert-group partials (exactly 2 addends on zeroed slot
    // -> bit-deterministic)
    if (lane < 32) {
        atomicAdd(&pred_out[tw + col],      pred0);
        atomicAdd(&pred_out[tw + 32 + col], pred1);
    }
}

// ---------------------------------------------------------------------------
extern "C" void kernel_launch(void* const* d_in, const int* in_sizes, int n_in,
                              void* d_out, int out_size, void* d_ws, size_t ws_size,
                              hipStream_t stream) {
    (void)in_sizes; (void)n_in; (void)out_size; (void)ws_size;
    const float* x  = (const float*)d_in[0];
    const float* cp = (const float*)d_in[1];
    const float* W1 = (const float*)d_in[2];
    const float* b1 = (const float*)d_in[3];
    const float* W2 = (const float*)d_in[4];
    const float* b2 = (const float*)d_in[5];

    float* out   = (float*)d_out;
    float* pred  = out;                       // [131072]
    float* gates = out + 131072;              // [131072*8]
    float* used  = out + 1179648;             // [131072]
    float* inf   = out + 1310720;             // [8]
    float* cnt   = out + 1310728;             // [8]

    unsigned short* wfrag = (unsigned short*)d_ws;           // 512 KB frag W1
    float* pk   = (float*)((char*)d_ws + 524288);            // 16 KB b1/w2 table
    float* part = (float*)((char*)d_ws + 540672);            // 32 KB partials

    prep_w1<<<dim3(1025), dim3(256), 0, stream>>>(W1, b1, W2, wfrag, pk);
    gates_kernel<<<dim3(512), dim3(256), 0, stream>>>(cp, gates, used, part, pred);
    reduce_kernel<<<dim3(1), dim3(512), 0, stream>>>(part, inf, cnt);
    moe_main<<<dim3(256), dim3(1024), 0, stream>>>(x, wfrag, pk, b2, gates, pred);
}

// Round 17
// 95.414 us; speedup vs baseline: 1.7920x; 1.7920x over previous
//
#include <hip/hip_runtime.h>
#include <math.h>

#define NE  8
#define HID 256

typedef __attribute__((ext_vector_type(8)))  short short8;
typedef __attribute__((ext_vector_type(16))) float f32x16;

static __device__ __forceinline__ unsigned short f2bf(float f) {
    unsigned int u = __float_as_uint(f);
    return (unsigned short)((u + 0x7FFFu + ((u >> 16) & 1u)) >> 16);
}

static __device__ __forceinline__ short8 pack8(float4 a, float4 b) {
    short8 r;
    r[0] = (short)f2bf(a.x); r[1] = (short)f2bf(a.y);
    r[2] = (short)f2bf(a.z); r[3] = (short)f2bf(a.w);
    r[4] = (short)f2bf(b.x); r[5] = (short)f2bf(b.y);
    r[6] = (short)f2bf(b.z); r[7] = (short)f2bf(b.w);
    return r;
}

// ---------------------------------------------------------------------------
// Kernel 1 (blocks 0..1023): W1 [E][128][256] -> bf16 frag-linear.
//   frag (e, hrt<8, kt<8): [lane][j] = W1[e][kt*16+(lane>>5)*8+j][hrt*32+(lane&31)]
// Block 1024: pk table [e][hrt][q][g][8] f32: j<4 -> b1[h], j>=4 -> W2[h].
// ---------------------------------------------------------------------------
__global__ void prep_w1(const float* __restrict__ W1, const float* __restrict__ b1,
                        const float* __restrict__ W2,
                        unsigned short* __restrict__ wfr, float* __restrict__ pk) {
    if (blockIdx.x < 1024) {
        int f = blockIdx.x * 256 + threadIdx.x;     // 262144 total
        int j   = f & 7;
        int l   = (f >> 3) & 63;
        int kt  = (f >> 9) & 7;
        int hrt = (f >> 12) & 7;
        int e   = f >> 15;
        int k = kt * 16 + ((l >> 5) * 8) + j;
        int h = hrt * 32 + (l & 31);
        wfr[f] = f2bf(W1[((size_t)e * 128 + k) * HID + h]);
    } else {
        for (int i = threadIdx.x; i < 4096; i += 256) {
            int j   = i & 7;
            int g   = (i >> 3) & 1;
            int q   = (i >> 4) & 3;
            int hrt = (i >> 6) & 7;
            int e   = i >> 9;
            int h = hrt * 32 + q * 8 + g * 4 + (j & 3);
            pk[i] = (j < 4) ? b1[e * HID + h] : W2[e * HID + h];
        }
    }
}

// ---------------------------------------------------------------------------
// Kernel 2: gating softmax (exact fp32) + experts_used + per-block partials
// ---------------------------------------------------------------------------
__global__ void gates_kernel(const float* __restrict__ cp,
                             float* __restrict__ gates_out,
                             float* __restrict__ used_out,
                             float* __restrict__ part) {
    __shared__ float wp_[4][16];
    int tid = threadIdx.x;
    int b = blockIdx.x * 256 + tid;

    float g[8];
    {
        const float4* c4 = (const float4*)(cp + (size_t)b * NE);
        float4 a0 = c4[0], a1 = c4[1];
        g[0]=a0.x; g[1]=a0.y; g[2]=a0.z; g[3]=a0.w;
        g[4]=a1.x; g[5]=a1.y; g[6]=a1.z; g[7]=a1.w;
    }
    float m = g[0];
    #pragma unroll
    for (int i = 1; i < 8; ++i) m = fmaxf(m, g[i]);
    float s = 0.f;
    #pragma unroll
    for (int i = 0; i < 8; ++i) { g[i] = __expf(g[i] - m); s += g[i]; }
    float inv = 1.f / s;
    #pragma unroll
    for (int i = 0; i < 8; ++i) g[i] *= inv;

    {
        float4 o0 = make_float4(g[0], g[1], g[2], g[3]);
        float4 o1 = make_float4(g[4], g[5], g[6], g[7]);
        float4* g4 = (float4*)(gates_out + (size_t)b * NE);
        g4[0] = o0; g4[1] = o1;
    }
    float v[16];
    float used = 0.f;
    #pragma unroll
    for (int i = 0; i < 8; ++i) {
        float a = (g[i] > 0.01f) ? 1.f : 0.f;
        used += a;
        v[i] = g[i];
        v[8 + i] = a;
    }
    used_out[b] = used;

    #pragma unroll
    for (int d = 32; d >= 1; d >>= 1)
        #pragma unroll
        for (int i = 0; i < 16; ++i)
            v[i] += __shfl_down(v[i], d, 64);
    int lane = tid & 63, wid = tid >> 6;
    if (lane == 0)
        #pragma unroll
        for (int i = 0; i < 16; ++i) wp_[wid][i] = v[i];
    __syncthreads();
    if (tid < 16)
        part[(size_t)blockIdx.x * 16 + tid] =
            wp_[0][tid] + wp_[1][tid] + wp_[2][tid] + wp_[3][tid];
}

// 512-thread deterministic reduce: 32 partial-threads per output, LDS tree.
__global__ void reduce_kernel(const float* __restrict__ part,
                              float* __restrict__ inf_out,
                              float* __restrict__ cnt_out) {
    __shared__ float red[16][32];
    int t = threadIdx.x;
    int o = t & 15, i = t >> 4;
    float s = 0.f;
    for (int k = i; k < 512; k += 32) s += part[(size_t)k * 16 + o];
    red[o][i] = s;
    __syncthreads();
    if (t < 16) {
        float r = 0.f;
        #pragma unroll
        for (int j = 0; j < 32; ++j) r += red[t][j];
        if (t < 8) inf_out[t] = r;
        else       cnt_out[t - 8] = r;
    }
}

// ---------------------------------------------------------------------------
// Kernel 4: main MoE = r9 body restructured into the 8-phase counted-vmcnt
// schedule (guide T3+T4+T5). Per expert, 8 phases; each phase:
//   {issue 1 staging chunk (8KB) of next expert -> s_waitcnt vmcnt(8)
//    (8 chunks stay in flight ACROSS barriers; never drains to 0)
//    -> raw s_barrier (asm, memory clobber -- NOT __syncthreads, whose
//    vmcnt(0) drain is the 2-phase structure's documented stall)
//    -> ds_read w1r -> setprio(1) 16 MFMA + prev-hrt epilogue setprio(0)}.
// e=7 issues dummy stages (expert 0) to keep the vmcnt count uniform at 8.
// e-loop fully unrolled so gates/b2 stay register-resident (no VMEM in the
// loop -> vmcnt counts only staging). 256 blocks x 512 thr, 64 tok/wave,
// LDS 144KB (2x64 dbuf + 16K f32 pks), direct stores (deterministic).
// ---------------------------------------------------------------------------
#define MFMA_ __builtin_amdgcn_mfma_f32_32x32x16_bf16

#define PHASE_PRE(E, H) { \
    const char* ssrc = (const char*)wfr + (size_t)(((E) + 1) & 7) * 65536 \
                     + (H) * 8192 + tid * 16; \
    char* sdst = (char*)&W1s[((E) + 1) & 1][0] + (H) * 8192 + tid * 16; \
    __builtin_amdgcn_global_load_lds( \
        (const __attribute__((address_space(1))) unsigned int*)ssrc, \
        (__attribute__((address_space(3))) unsigned int*)sdst, 16, 0, 0); \
    asm volatile("s_waitcnt vmcnt(8)" ::: "memory"); \
    asm volatile("s_barrier" ::: "memory"); \
}

#define STEP(E, HRT, C0, C1, P0, P1, PH) { \
    float4 b1q, w2q; \
    __builtin_amdgcn_s_setprio(1); \
    _Pragma("unroll") \
    for (int kt = 0; kt < 8; ++kt) { \
        short8 w = *(const short8*)&W1s[(E) & 1][(((HRT) * 8 + kt) * 64 + lane) * 8]; \
        C0 = MFMA_(w, xf[0][kt], C0, 0, 0, 0); \
        C1 = MFMA_(w, xf[1][kt], C1, 0, 0, 0); \
        int q = kt >> 1; \
        if ((kt & 1) == 0) { \
            int base = ((((E) * 8 + (PH)) * 4 + q) * 2 + g) * 8; \
            b1q = *(const float4*)&pks[base]; \
            w2q = *(const float4*)&pks[base + 4]; \
            ye0 = fmaf(fmaxf(P0[q * 4 + 0] + b1q.x, 0.f), w2q.x, ye0); \
            ye1 = fmaf(fmaxf(P1[q * 4 + 0] + b1q.x, 0.f), w2q.x, ye1); \
            ye0 = fmaf(fmaxf(P0[q * 4 + 1] + b1q.y, 0.f), w2q.y, ye0); \
            ye1 = fmaf(fmaxf(P1[q * 4 + 1] + b1q.y, 0.f), w2q.y, ye1); \
        } else { \
            ye0 = fmaf(fmaxf(P0[q * 4 + 2] + b1q.z, 0.f), w2q.z, ye0); \
            ye1 = fmaf(fmaxf(P1[q * 4 + 2] + b1q.z, 0.f), w2q.z, ye1); \
            ye0 = fmaf(fmaxf(P0[q * 4 + 3] + b1q.w, 0.f), w2q.w, ye0); \
            ye1 = fmaf(fmaxf(P1[q * 4 + 3] + b1q.w, 0.f), w2q.w, ye1); \
        } \
    } \
    __builtin_amdgcn_s_setprio(0); \
}

#define STEP_NOEPI(E, HRT, C0, C1) { \
    __builtin_amdgcn_s_setprio(1); \
    _Pragma("unroll") \
    for (int kt = 0; kt < 8; ++kt) { \
        short8 w = *(const short8*)&W1s[(E) & 1][(((HRT) * 8 + kt) * 64 + lane) * 8]; \
        C0 = MFMA_(w, xf[0][kt], C0, 0, 0, 0); \
        C1 = MFMA_(w, xf[1][kt], C1, 0, 0, 0); \
    } \
    __builtin_amdgcn_s_setprio(0); \
}

#define EPI_TAIL(E, P0, P1, PH) { \
    _Pragma("unroll") \
    for (int q = 0; q < 4; ++q) { \
        int base = ((((E) * 8 + (PH)) * 4 + q) * 2 + g) * 8; \
        float4 b1q = *(const float4*)&pks[base]; \
        float4 w2q = *(const float4*)&pks[base + 4]; \
        ye0 = fmaf(fmaxf(P0[q * 4 + 0] + b1q.x, 0.f), w2q.x, ye0); \
        ye1 = fmaf(fmaxf(P1[q * 4 + 0] + b1q.x, 0.f), w2q.x, ye1); \
        ye0 = fmaf(fmaxf(P0[q * 4 + 1] + b1q.y, 0.f), w2q.y, ye0); \
        ye1 = fmaf(fmaxf(P1[q * 4 + 1] + b1q.y, 0.f), w2q.y, ye1); \
        ye0 = fmaf(fmaxf(P0[q * 4 + 2] + b1q.z, 0.f), w2q.z, ye0); \
        ye1 = fmaf(fmaxf(P1[q * 4 + 2] + b1q.z, 0.f), w2q.z, ye1); \
        ye0 = fmaf(fmaxf(P0[q * 4 + 3] + b1q.w, 0.f), w2q.w, ye0); \
        ye1 = fmaf(fmaxf(P1[q * 4 + 3] + b1q.w, 0.f), w2q.w, ye1); \
    } }

// one full expert: 8 phases + tail fold
#define EXPERT(E) { \
    float ye0 = 0.f, ye1 = 0.f; \
    f32x16 a0, a1, c0, c1; \
    PHASE_PRE(E, 0) \
    a0 = (f32x16)0.0f; a1 = (f32x16)0.0f; \
    STEP_NOEPI(E, 0, a0, a1) \
    PHASE_PRE(E, 1) \
    c0 = (f32x16)0.0f; c1 = (f32x16)0.0f; \
    STEP(E, 1, c0, c1, a0, a1, 0) \
    PHASE_PRE(E, 2) \
    a0 = (f32x16)0.0f; a1 = (f32x16)0.0f; \
    STEP(E, 2, a0, a1, c0, c1, 1) \
    PHASE_PRE(E, 3) \
    c0 = (f32x16)0.0f; c1 = (f32x16)0.0f; \
    STEP(E, 3, c0, c1, a0, a1, 2) \
    PHASE_PRE(E, 4) \
    a0 = (f32x16)0.0f; a1 = (f32x16)0.0f; \
    STEP(E, 4, a0, a1, c0, c1, 3) \
    PHASE_PRE(E, 5) \
    c0 = (f32x16)0.0f; c1 = (f32x16)0.0f; \
    STEP(E, 5, c0, c1, a0, a1, 4) \
    PHASE_PRE(E, 6) \
    a0 = (f32x16)0.0f; a1 = (f32x16)0.0f; \
    STEP(E, 6, a0, a1, c0, c1, 5) \
    PHASE_PRE(E, 7) \
    c0 = (f32x16)0.0f; c1 = (f32x16)0.0f; \
    STEP(E, 7, c0, c1, a0, a1, 6) \
    EPI_TAIL(E, c0, c1, 7) \
    { \
        float s0 = ye0 + __shfl_xor(ye0, 32, 64) + b2v[E]; \
        float s1 = ye1 + __shfl_xor(ye1, 32, 64) + b2v[E]; \
        float yv0 = 1.f / (1.f + __expf(-s0)); \
        float yv1 = 1.f / (1.f + __expf(-s1)); \
        pred0 = fmaf(gts0[E], yv0, pred0); \
        pred1 = fmaf(gts1[E], yv1, pred1); \
    } }

__global__ __launch_bounds__(512, 2)
void moe_main(const float* __restrict__ x,
              const unsigned short* __restrict__ wfr,
              const float* __restrict__ pk,
              const float* __restrict__ b2,
              const float* __restrict__ gates,
              float* __restrict__ pred_out) {
    __shared__ unsigned short W1s[2][8 * 8 * 64 * 8];   // 2 x 64 KB
    __shared__ float pks[4096];                         // 16 KB

    const int tid  = threadIdx.x;
    const int lane = tid & 63;
    const int wid  = tid >> 6;          // 0..7
    const int g    = lane >> 5;
    const int col  = lane & 31;
    const int tw   = blockIdx.x * 512 + wid * 64;   // wave token base

    // ---- stage expert 0 into buf 0 (64 KB = 512 thr x 8 x 16B, chunk-major)
    {
        const char* src = (const char*)wfr + tid * 16;
        char* dst = (char*)&W1s[0][0] + tid * 16;
        #pragma unroll
        for (int i = 0; i < 8; ++i)
            __builtin_amdgcn_global_load_lds(
                (const __attribute__((address_space(1))) unsigned int*)(src + i * 8192),
                (__attribute__((address_space(3))) unsigned int*)(dst + i * 8192),
                16, 0, 0);
    }
    // ---- pk table -> LDS (1024 float4)
    ((float4*)pks)[tid]       = ((const float4*)pk)[tid];
    ((float4*)pks)[tid + 512] = ((const float4*)pk)[tid + 512];

    // ---- x fragments -> registers
    short8 xf[2][8];
    #pragma unroll
    for (int tt = 0; tt < 2; ++tt) {
        const float* xr = x + ((size_t)(tw + tt * 32 + col)) * 128 + g * 8;
        #pragma unroll
        for (int kt = 0; kt < 8; ++kt) {
            float4 a = *(const float4*)(xr + kt * 16);
            float4 b = *(const float4*)(xr + kt * 16 + 4);
            xf[tt][kt] = pack8(a, b);
        }
    }

    // ---- per-expert scalars hoisted to registers (keeps loop VMEM-free so
    //      vmcnt counts ONLY staging loads)
    float gts0[8], gts1[8], b2v[8];
    {
        const float4* ga = (const float4*)(gates + (size_t)(tw + col) * NE);
        const float4* gb = (const float4*)(gates + (size_t)(tw + 32 + col) * NE);
        float4 a0 = ga[0], a1 = ga[1], b0 = gb[0], b1 = gb[1];
        gts0[0]=a0.x; gts0[1]=a0.y; gts0[2]=a0.z; gts0[3]=a0.w;
        gts0[4]=a1.x; gts0[5]=a1.y; gts0[6]=a1.z; gts0[7]=a1.w;
        gts1[0]=b0.x; gts1[1]=b0.y; gts1[2]=b0.z; gts1[3]=b0.w;
        gts1[4]=b1.x; gts1[5]=b1.y; gts1[6]=b1.z; gts1[7]=b1.w;
        #pragma unroll
        for (int i = 0; i < 8; ++i) b2v[i] = b2[i];
    }

    float pred0 = 0.f, pred1 = 0.f;
    __syncthreads();   // prologue drain: stage(e0), pks, x, gates, b2

    EXPERT(0) EXPERT(1) EXPERT(2) EXPERT(3)
    EXPERT(4) EXPERT(5) EXPERT(6) EXPERT(7)

    if (lane < 32) {
        pred_out[tw + col]      = pred0;
        pred_out[tw + 32 + col] = pred1;
    }
}

// ---------------------------------------------------------------------------
extern "C" void kernel_launch(void* const* d_in, const int* in_sizes, int n_in,
                              void* d_out, int out_size, void* d_ws, size_t ws_size,
                              hipStream_t stream) {
    (void)in_sizes; (void)n_in; (void)out_size; (void)ws_size;
    const float* x  = (const float*)d_in[0];
    const float* cp = (const float*)d_in[1];
    const float* W1 = (const float*)d_in[2];
    const float* b1 = (const float*)d_in[3];
    const float* W2 = (const float*)d_in[4];
    const float* b2 = (const float*)d_in[5];

    float* out   = (float*)d_out;
    float* pred  = out;                       // [131072]
    float* gates = out + 131072;              // [131072*8]
    float* used  = out + 1179648;             // [131072]
    float* inf   = out + 1310720;             // [8]
    float* cnt   = out + 1310728;             // [8]

    unsigned short* wfrag = (unsigned short*)d_ws;           // 512 KB frag W1
    float* pk   = (float*)((char*)d_ws + 524288);            // 16 KB b1/w2 table
    float* part = (float*)((char*)d_ws + 540672);            // 32 KB partials

    prep_w1<<<dim3(1025), dim3(256), 0, stream>>>(W1, b1, W2, wfrag, pk);
    gates_kernel<<<dim3(512), dim3(256), 0, stream>>>(cp, gates, used, part);
    reduce_kernel<<<dim3(1), dim3(512), 0, stream>>>(part, inf, cnt);
    moe_main<<<dim3(256), dim3(512), 0, stream>>>(x, wfrag, pk, b2, gates, pred);
}